// Round 11
// baseline (514.024 us; speedup 1.0000x reference)
//
#include <hip/hip_runtime.h>

#define N_NODES 100000
#define N_EDGES 3200000
#define BATCH 16384
#define MAX_SLOTS 32768
#define MAGIC 0x5A5A5A5Au

#define GRID 512
#define TPB 512

// Degree histogram: nibble-packed, all 100K nodes in 50 KB LDS, 256 slices x 12500 edges.
#define NW 12500        // nibble words (8 nodes/word)
#define HSLICES 256
// Scatter: 512 sub-slices x 6250 edges (int2-aligned).
#define NSUB 512
#define NBUCK 256
#define BSH 7

// Workspace layout (byte offsets). ws_size = 256 MiB.
#define OFF_SLOT      0          // 100000 u32
#define OFF_COUNTERS  400000     // 16 ints: [0]=nSlots, [1]=grid barrier counter
#define OFF_DINV      400064     // 100000 f32
#define OFF_NODELIST  800064     // 32768 ints
#define OFF_BTOT      931136     // 256 ints
#define OFF_BPART     932160     // 256 x 512 ints [bucket][subslice]
#define OFF_SLOTSTART 1456448    // 32769 ints
#define OFF_PARTIALS  1587584    // 256 x 12500 words = 12.8 MB nibble degree counts
#define OFF_WH        14387584   // bf16 w*dinv, 100000x64x2 B
#define OFF_BINS      27187584   // packed (slot_local<<17|src), cap 1.2M
#define OFF_BINS2     31987584   // slot-sorted src ids, cap 1.2M
#define OFF_EMB       36787584   // bf16 32768x64

__device__ __forceinline__ unsigned bfr(float f) {   // fp32 -> bf16 bits, RNE
    unsigned u = __float_as_uint(f);
    return (u + 0x7FFFu + ((u >> 16) & 1u)) >> 16;
}
__device__ __forceinline__ float bfx(unsigned h) {   // low 16 bits -> fp32
    return __uint_as_float(h << 16);
}

// Software grid barrier: monotone counter, device-scope atomics (coherence point),
// threadfence for cross-XCD visibility. All GRID blocks are co-resident by
// construction (grid == exact 2-blocks/CU capacity enforced via launch_bounds+LDS).
__device__ __forceinline__ void gbar(int* cnt, int target) {
    __syncthreads();
    if (threadIdx.x == 0) {
        __threadfence();
        atomicAdd(cnt, 1);
        while (atomicAdd(cnt, 0) < target) __builtin_amdgcn_s_sleep(8);
        __threadfence();
    }
    __syncthreads();
}

// Launch 1: zero counters (incl. barrier counter) + mark needed nodes with MAGIC.
__global__ void k_init0(const int* __restrict__ pairs, unsigned* __restrict__ slot,
                        int* __restrict__ counters) {
    int i = blockIdx.x * blockDim.x + threadIdx.x;
    if (i < 16) counters[i] = 0;
    if (i < 2 * BATCH) slot[pairs[i]] = MAGIC;
}

__global__ __launch_bounds__(TPB, 4) void k_mega(
        const float4* __restrict__ w4, const float4* __restrict__ bias4,
        const float* __restrict__ lw, const float* __restrict__ lb,
        const int* __restrict__ src, const int* __restrict__ dst,
        const int* __restrict__ pairs, float* __restrict__ out, char* __restrict__ ws) {
    unsigned* slot      = (unsigned*)(ws + OFF_SLOT);
    int*      counters  = (int*)     (ws + OFF_COUNTERS);
    float*    dinv      = (float*)   (ws + OFF_DINV);
    int*      nodelist  = (int*)     (ws + OFF_NODELIST);
    int*      btot      = (int*)     (ws + OFF_BTOT);
    int*      bpart     = (int*)     (ws + OFF_BPART);
    int*      slotstart = (int*)     (ws + OFF_SLOTSTART);
    unsigned* partials  = (unsigned*)(ws + OFF_PARTIALS);
    uint4*    wh4       = (uint4*)   (ws + OFF_WH);
    int*      bins      = (int*)     (ws + OFF_BINS);
    int*      bins2     = (int*)     (ws + OFF_BINS2);
    uint4*    emb4      = (uint4*)   (ws + OFF_EMB);
    const uint2* emb2   = (const uint2*)(ws + OFF_EMB);
    int* cnt = &counters[1];

    __shared__ union SM {
        struct { unsigned h[NW]; int lc[2][NBUCK]; } c;                 // 52048 B max
        struct { unsigned p[4][TPB]; float sdinv[256]; } d;
        struct { int t[NSUB]; } pfx;
        struct { int tb[NBUCK], vv[NBUCK], cur[NBUCK]; } e;
        struct { int tb[NBUCK], vv[NBUCK], lc[128], st[128]; } f;
    } sm;

    int tid = threadIdx.x;

    // ---- Phase B: wave-aggregated compaction (writes every slot) ----
    {
        int n = blockIdx.x * TPB + tid;
        int lane = tid & 63;
        int want = (n < N_NODES && slot[n] == MAGIC) ? 1 : 0;
        int incl = want;
#pragma unroll
        for (int d = 1; d < 64; d <<= 1) {
            int t = __shfl_up(incl, d, 64);
            if (lane >= d) incl += t;
        }
        int total = __shfl(incl, 63, 64);
        int base = 0;
        if (lane == 63 && total > 0) base = atomicAdd(&counters[0], total);
        base = __shfl(base, 63, 64);
        if (n < N_NODES) {
            if (want) {
                int s = base + incl - 1;
                slot[n] = (unsigned)(s + 1);
                nodelist[s] = n;
            } else {
                slot[n] = 0u;
            }
        }
    }
    gbar(cnt, GRID);

    // ---- Phase C: nibble degree hist (all nodes) + per-half-slice bucket counts ----
    if (blockIdx.x < HSLICES) {
        int g = blockIdx.x;
        for (int i = tid; i < NW; i += TPB) sm.c.h[i] = 0;
        if (tid < NBUCK) { sm.c.lc[0][tid] = 0; sm.c.lc[1][tid] = 0; }
        __syncthreads();
        const int4* d4 = (const int4*)(dst + g * 12500);
        for (int i = tid; i < 3125; i += TPB) {
            int4 v = d4[i];
            atomicAdd(&sm.c.h[v.x >> 3], 1u << ((v.x & 7) << 2));
            atomicAdd(&sm.c.h[v.y >> 3], 1u << ((v.y & 7) << 2));
            atomicAdd(&sm.c.h[v.z >> 3], 1u << ((v.z & 7) << 2));
            atomicAdd(&sm.c.h[v.w >> 3], 1u << ((v.w & 7) << 2));
            int s01 = (i * 4) >= 6250;
            int s23 = (i * 4 + 2) >= 6250;
            unsigned r;
            r = slot[v.x]; if (r) atomicAdd(&sm.c.lc[s01][(r - 1) >> BSH], 1);
            r = slot[v.y]; if (r) atomicAdd(&sm.c.lc[s01][(r - 1) >> BSH], 1);
            r = slot[v.z]; if (r) atomicAdd(&sm.c.lc[s23][(r - 1) >> BSH], 1);
            r = slot[v.w]; if (r) atomicAdd(&sm.c.lc[s23][(r - 1) >> BSH], 1);
        }
        __syncthreads();
        unsigned* outp = partials + (unsigned)g * NW;
        for (int i = tid; i < NW; i += TPB) outp[i] = sm.c.h[i];
        if (tid < NBUCK) {
            bpart[tid * NSUB + g * 2]     = sm.c.lc[0][tid];
            bpart[tid * NSUB + g * 2 + 1] = sm.c.lc[1][tid];
        }
    }
    gbar(cnt, 2 * GRID);

    // ---- Phase D: blocks <391: partials -> dinv + bf16 wh; blocks >=391: bucket row scans ----
    if (blockIdx.x < 391) {
        int wi = tid & 31, sg = tid >> 5;             // word-in-block, slice-group (16 groups x 16)
        int w = blockIdx.x * 32 + wi;
        unsigned A = 0, Bu = 0, Cu = 0, Du = 0;
        if (w < NW) {
            const unsigned* q = partials + w;
            unsigned x = 0, y = 0;
#pragma unroll
            for (int k = 0; k < 16; ++k) {
                unsigned v = q[(unsigned)(sg * 16 + k) * NW];
                x += v & 0x0F0F0F0Fu;
                y += (v >> 4) & 0x0F0F0F0Fu;
            }
            A = x & 0x00FF00FFu; Bu = (x >> 8) & 0x00FF00FFu;
            Cu = y & 0x00FF00FFu; Du = (y >> 8) & 0x00FF00FFu;
        }
        sm.d.p[0][tid] = A; sm.d.p[1][tid] = Bu; sm.d.p[2][tid] = Cu; sm.d.p[3][tid] = Du;
        __syncthreads();
        if (tid < 32 && w < NW) {
            unsigned sA = 0, sB = 0, sC = 0, sD = 0;
#pragma unroll
            for (int k = 0; k < 16; ++k) {
                sA += sm.d.p[0][k * 32 + tid]; sB += sm.d.p[1][k * 32 + tid];
                sC += sm.d.p[2][k * 32 + tid]; sD += sm.d.p[3][k * 32 + tid];
            }
            float4 d0, d1;
            d0.x = rsqrtf((float)(sA & 0xFFFFu) + 1.0f);
            d0.y = rsqrtf((float)(sC & 0xFFFFu) + 1.0f);
            d0.z = rsqrtf((float)(sB & 0xFFFFu) + 1.0f);
            d0.w = rsqrtf((float)(sD & 0xFFFFu) + 1.0f);
            d1.x = rsqrtf((float)(sA >> 16) + 1.0f);
            d1.y = rsqrtf((float)(sC >> 16) + 1.0f);
            d1.z = rsqrtf((float)(sB >> 16) + 1.0f);
            d1.w = rsqrtf((float)(sD >> 16) + 1.0f);
            ((float4*)dinv)[w * 2] = d0;
            ((float4*)dinv)[w * 2 + 1] = d1;
            int lbm = tid * 8;
            sm.d.sdinv[lbm + 0] = d0.x; sm.d.sdinv[lbm + 1] = d0.y;
            sm.d.sdinv[lbm + 2] = d0.z; sm.d.sdinv[lbm + 3] = d0.w;
            sm.d.sdinv[lbm + 4] = d1.x; sm.d.sdinv[lbm + 5] = d1.y;
            sm.d.sdinv[lbm + 6] = d1.z; sm.d.sdinv[lbm + 7] = d1.w;
        }
        __syncthreads();
#pragma unroll
        for (int it = 0; it < 4; ++it) {
            int k = blockIdx.x * 2048 + it * TPB + tid;   // uint4 idx (8 dims); node = k>>3
            if (k < N_NODES * 8) {
                float4 va = w4[k * 2];
                float4 vb = w4[k * 2 + 1];
                float d = sm.d.sdinv[(k >> 3) - blockIdx.x * 256];
                uint4 o;
                o.x = bfr(va.x * d) | (bfr(va.y * d) << 16);
                o.y = bfr(va.z * d) | (bfr(va.w * d) << 16);
                o.z = bfr(vb.x * d) | (bfr(vb.y * d) << 16);
                o.w = bfr(vb.z * d) | (bfr(vb.w * d) << 16);
                wh4[k] = o;
            }
        }
    } else {
        for (int r = blockIdx.x - 391; r < NBUCK; r += 121) {
            int v = bpart[r * NSUB + tid];
            sm.pfx.t[tid] = v;
            __syncthreads();
            for (int off = 1; off < NSUB; off <<= 1) {
                int x = (tid >= off) ? sm.pfx.t[tid - off] : 0;
                __syncthreads();
                sm.pfx.t[tid] += x;
                __syncthreads();
            }
            bpart[r * NSUB + tid] = sm.pfx.t[tid] - v;
            if (tid == NSUB - 1) btot[r] = sm.pfx.t[tid];
            __syncthreads();
        }
    }
    gbar(cnt, 3 * GRID);

    // ---- Phase E: deterministic scatter (512 sub-slices of 6250 edges, int2) ----
    {
        int u = blockIdx.x;
        if (tid < NBUCK) { int v = btot[tid]; sm.e.vv[tid] = v; sm.e.tb[tid] = v; }
        __syncthreads();
        for (int off = 1; off < NBUCK; off <<= 1) {
            int x = (tid < NBUCK && tid >= off) ? sm.e.tb[tid - off] : 0;
            __syncthreads();
            if (tid < NBUCK) sm.e.tb[tid] += x;
            __syncthreads();
        }
        if (tid < NBUCK) sm.e.cur[tid] = sm.e.tb[tid] - sm.e.vv[tid] + bpart[tid * NSUB + u];
        __syncthreads();
        const int2* d2 = (const int2*)(dst + u * 6250);
        const int2* s2 = (const int2*)(src + u * 6250);
        for (int i = tid; i < 3125; i += TPB) {
            int2 d = d2[i];
            int2 s = s2[i];
            unsigned r;
            r = slot[d.x];
            if (r) {
                int sl = (int)r - 1;
                int pos = atomicAdd(&sm.e.cur[sl >> BSH], 1);
                bins[pos] = ((sl & 127) << 17) | s.x;
            }
            r = slot[d.y];
            if (r) {
                int sl = (int)r - 1;
                int pos = atomicAdd(&sm.e.cur[sl >> BSH], 1);
                bins[pos] = ((sl & 127) << 17) | s.y;
            }
        }
    }
    gbar(cnt, 4 * GRID);

    // ---- Phase F: per-bucket counting sort -> per-slot CSR ----
    if (blockIdx.x < NBUCK) {
        int b = blockIdx.x;
        if (tid < NBUCK) { int v = btot[tid]; sm.f.vv[tid] = v; sm.f.tb[tid] = v; }
        __syncthreads();
        for (int off = 1; off < NBUCK; off <<= 1) {
            int x = (tid < NBUCK && tid >= off) ? sm.f.tb[tid - off] : 0;
            __syncthreads();
            if (tid < NBUCK) sm.f.tb[tid] += x;
            __syncthreads();
        }
        int beg = sm.f.tb[b] - sm.f.vv[b];
        int end = beg + sm.f.vv[b];
        if (tid < 128) sm.f.lc[tid] = 0;
        __syncthreads();
        for (int j = beg + tid; j < end; j += TPB)
            atomicAdd(&sm.f.lc[(bins[j] >> 17) & 127], 1);
        __syncthreads();
        if (tid < 128) sm.f.st[tid] = sm.f.lc[tid];
        __syncthreads();
        for (int off = 1; off < 128; off <<= 1) {
            int v = (tid < 128 && tid >= off) ? sm.f.st[tid - off] : 0;
            __syncthreads();
            if (tid < 128) sm.f.st[tid] += v;
            __syncthreads();
        }
        if (tid < 128) {
            int s0 = beg + sm.f.st[tid] - sm.f.lc[tid];
            slotstart[(b << 7) + tid] = s0;
            sm.f.lc[tid] = s0;
        }
        if (b == NBUCK - 1 && tid == 0) slotstart[MAX_SLOTS] = sm.f.tb[NBUCK - 1];
        __syncthreads();
        for (int j = beg + tid; j < end; j += TPB) {
            int e = bins[j];
            int pos = atomicAdd(&sm.f.lc[(e >> 17) & 127], 1);
            bins2[pos] = e & 0x1FFFF;
        }
    }
    gbar(cnt, 5 * GRID);

    // ---- Phase G: gather (wave per slot, grid-stride; uint4 = 8 rows/instr) ----
    {
        int nS = counters[0];
        int wv = blockIdx.x * (TPB / 64) + (tid >> 6);
        int lane = tid & 63;
        int rg = lane >> 3, dp = lane & 7;
        for (int s = wv; s < nS; s += GRID * (TPB / 64)) {
            int beg = slotstart[s], end = slotstart[s + 1];
            float a0 = 0.f, a1 = 0.f, a2 = 0.f, a3 = 0.f,
                  a4 = 0.f, a5 = 0.f, a6 = 0.f, a7 = 0.f;
            int j = beg;
            for (; j + 16 <= end; j += 16) {
                int e0 = bins2[j + rg];
                int e1 = bins2[j + 8 + rg];
                uint4 oa = wh4[(e0 << 3) + dp];
                uint4 ob = wh4[(e1 << 3) + dp];
                a0 += bfx(oa.x) + bfx(ob.x);
                a1 += bfx(oa.x >> 16) + bfx(ob.x >> 16);
                a2 += bfx(oa.y) + bfx(ob.y);
                a3 += bfx(oa.y >> 16) + bfx(ob.y >> 16);
                a4 += bfx(oa.z) + bfx(ob.z);
                a5 += bfx(oa.z >> 16) + bfx(ob.z >> 16);
                a6 += bfx(oa.w) + bfx(ob.w);
                a7 += bfx(oa.w >> 16) + bfx(ob.w >> 16);
            }
            for (; j < end; j += 8) {
                if (rg < end - j) {
                    int e0 = bins2[j + rg];
                    uint4 oa = wh4[(e0 << 3) + dp];
                    a0 += bfx(oa.x); a1 += bfx(oa.x >> 16);
                    a2 += bfx(oa.y); a3 += bfx(oa.y >> 16);
                    a4 += bfx(oa.z); a5 += bfx(oa.z >> 16);
                    a6 += bfx(oa.w); a7 += bfx(oa.w >> 16);
                }
            }
#pragma unroll
            for (int m = 8; m <= 32; m <<= 1) {
                a0 += __shfl_xor(a0, m, 64); a1 += __shfl_xor(a1, m, 64);
                a2 += __shfl_xor(a2, m, 64); a3 += __shfl_xor(a3, m, 64);
                a4 += __shfl_xor(a4, m, 64); a5 += __shfl_xor(a5, m, 64);
                a6 += __shfl_xor(a6, m, 64); a7 += __shfl_xor(a7, m, 64);
            }
            if (rg == 0) {
                int n = nodelist[s];
                float dn = dinv[n];
                uint4 u = wh4[(n << 3) + dp];
                float4 b0 = bias4[dp * 2], b1 = bias4[dp * 2 + 1];
                float r0 = (a0 + bfx(u.x)) * dn + b0.x;
                float r1 = (a1 + bfx(u.x >> 16)) * dn + b0.y;
                float r2 = (a2 + bfx(u.y)) * dn + b0.z;
                float r3 = (a3 + bfx(u.y >> 16)) * dn + b0.w;
                float r4 = (a4 + bfx(u.z)) * dn + b1.x;
                float r5 = (a5 + bfx(u.z >> 16)) * dn + b1.y;
                float r6 = (a6 + bfx(u.w)) * dn + b1.z;
                float r7 = (a7 + bfx(u.w >> 16)) * dn + b1.w;
                uint4 o;
                o.x = bfr(r0) | (bfr(r1) << 16);
                o.y = bfr(r2) | (bfr(r3) << 16);
                o.z = bfr(r4) | (bfr(r5) << 16);
                o.w = bfr(r6) | (bfr(r7) << 16);
                emb4[(s << 3) + dp] = o;
            }
        }
    }
    gbar(cnt, 6 * GRID);

    // ---- Phase H: FM dot + linear (4 pairs per wave, 16 lanes each) ----
    {
        int p = (blockIdx.x * TPB + tid) >> 4;
        int li = tid & 15;
        if (p < BATCH) {
            int a = pairs[p * 2], b = pairs[p * 2 + 1];
            int sa = (int)slot[a] - 1;
            int sb = (int)slot[b] - 1;
            uint2 ua = emb2[(sa << 4) + li];
            uint2 ub = emb2[(sb << 4) + li];
            float prod = bfx(ua.x) * bfx(ub.x) + bfx(ua.x >> 16) * bfx(ub.x >> 16)
                       + bfx(ua.y) * bfx(ub.y) + bfx(ua.y >> 16) * bfx(ub.y >> 16);
#pragma unroll
            for (int m = 1; m <= 8; m <<= 1) prod += __shfl_xor(prod, m, 64);
            if (li == 0) out[p] = lw[a] + lw[b] + lb[0] + prod;
        }
    }
}

extern "C" void kernel_launch(void* const* d_in, const int* in_sizes, int n_in,
                              void* d_out, int out_size, void* d_ws, size_t ws_size,
                              hipStream_t stream) {
    const float* gcn_weight    = (const float*)d_in[0];
    const float* gcn_bias      = (const float*)d_in[1];
    const float* linear_weight = (const float*)d_in[2];
    const float* linear_bias   = (const float*)d_in[3];
    const int*   edge_index    = (const int*)d_in[4];
    const int*   pairs         = (const int*)d_in[5];
    float* out = (float*)d_out;

    char* ws = (char*)d_ws;
    unsigned* slot     = (unsigned*)(ws + OFF_SLOT);
    int*      counters = (int*)     (ws + OFF_COUNTERS);

    const int* src_arr = edge_index;
    const int* dst_arr = edge_index + N_EDGES;

    k_init0<<<128, 256, 0, stream>>>(pairs, slot, counters);
    k_mega<<<GRID, TPB, 0, stream>>>((const float4*)gcn_weight, (const float4*)gcn_bias,
                                     linear_weight, linear_bias, src_arr, dst_arr,
                                     pairs, out, ws);
}